// Round 5
// baseline (55.379 us; speedup 1.0000x reference)
//
#include <hip/hip_runtime.h>

// SmoothnessLoss: error = sum_{c,h,w} x*(1 - cnt(h,w)*w) / (H*W)
// cnt(h,w) = nh*nw - 1, nh = 3-(h==0)-(h==H-1), nw = 3-(w==0)-(w==W-1).
// Derivation: summing the 8-neighbor gather over all pixels counts each
// wx[y,x'] once per valid neighbor slot == size of its own neighborhood.
//
// R5 = R4's streaming body, but the serial tail kernel is replaced with a
// single fire-and-forget RELAXED float atomicAdd per block (device-scope
// RMW at the coherence point -- none of R3's acq/rel L2-maintenance+polling).
// Each block contributes partial/(H*W) (~2e-5), so f32 accumulation noise
// is ~1e-9, four orders below the 2.4e-5 threshold. d_out is zeroed by a
// graph-capturable async memset each launch (harness does not re-poison).

#define HDIM 4096
#define WDIM 4096
#define NBLOCKS 2048
#define NTHREADS 256
#define N4 ((2 * HDIM * WDIM) / 4)
#define STRIDE (NBLOCKS * NTHREADS)
#define ITERS (N4 / STRIDE)   // = 16
#define BATCH 4

__global__ __launch_bounds__(NTHREADS) void smooth_kernel(
    const float4* __restrict__ x4,
    const float4* __restrict__ w4,
    float* __restrict__ out)
{
    int tid = blockIdx.x * blockDim.x + threadIdx.x;

    double acc0 = 0.0, acc1 = 0.0, acc2 = 0.0, acc3 = 0.0;

    #pragma unroll
    for (int b = 0; b < ITERS; b += BATCH) {
        float4 xv[BATCH], wv[BATCH];
        #pragma unroll
        for (int k = 0; k < BATCH; ++k) {
            int i = tid + (b + k) * STRIDE;
            xv[k] = x4[i];
            wv[k] = w4[i];
        }
        #pragma unroll
        for (int k = 0; k < BATCH; ++k) {
            int i  = tid + (b + k) * STRIDE;
            int e  = i << 2;                 // flat element index of .x
            int ww = e & (WDIM - 1);         // column of .x
            int h  = (e >> 12) & (HDIM - 1); // row

            float nh  = 3.0f - (h == 0) - (h == HDIM - 1);
            float nw0 = (ww == 0)        ? 2.0f : 3.0f;
            float nw3 = (ww == WDIM - 4) ? 2.0f : 3.0f;
            float m1  = nh * 3.0f - 1.0f;

            acc0 += (double)(xv[k].x * (1.0f - (nh * nw0 - 1.0f) * wv[k].x));
            acc1 += (double)(xv[k].y * (1.0f - m1 * wv[k].y));
            acc2 += (double)(xv[k].z * (1.0f - m1 * wv[k].z));
            acc3 += (double)(xv[k].w * (1.0f - (nh * nw3 - 1.0f) * wv[k].w));
        }
    }

    double acc = (acc0 + acc1) + (acc2 + acc3);

    // wave(64) reduce
    for (int off = 32; off > 0; off >>= 1)
        acc += __shfl_down(acc, off, 64);

    __shared__ double lds[NTHREADS / 64];
    int lane = threadIdx.x & 63;
    int wid  = threadIdx.x >> 6;
    if (lane == 0) lds[wid] = acc;
    __syncthreads();

    if (threadIdx.x == 0) {
        double s = (lds[0] + lds[1]) + (lds[2] + lds[3]);
        float contrib = (float)(s * (1.0 / ((double)HDIM * (double)WDIM)));
        atomicAdd(out, contrib);   // relaxed device-scope RMW, no fences
    }
}

extern "C" void kernel_launch(void* const* d_in, const int* in_sizes, int n_in,
                              void* d_out, int out_size, void* d_ws, size_t ws_size,
                              hipStream_t stream) {
    const float4* x4 = (const float4*)d_in[0];
    const float4* w4 = (const float4*)d_in[1];
    float* out = (float*)d_out;

    (void)in_sizes; (void)n_in; (void)out_size; (void)d_ws; (void)ws_size;

    hipMemsetAsync(out, 0, sizeof(float), stream);  // graph-capturable node
    smooth_kernel<<<NBLOCKS, NTHREADS, 0, stream>>>(x4, w4, out);
}

// Round 6
// 50.798 us; speedup vs baseline: 1.0902x; 1.0902x over previous
//
#include <hip/hip_runtime.h>

// SmoothnessLoss: error = sum_{c,h,w} x*(1 - cnt(h,w)*w) / (H*W)
// cnt(h,w) = nh*nw - 1, nh = 3-(h==0)-(h==H-1), nw = 3-(w==0)-(w==W-1).
// Derivation: summing the 8-neighbor gather over all pixels counts each
// wx[y,x'] once per valid neighbor slot == size of its own neighborhood.
//
// R6 = exact revert to R4 (best: 47.3us). Two kernels, plain partial
// stores + tiny dependent reduce kernel. Tail-fusion alternatives are
// falsified: R3 acq/rel ticket = +125us (L2 cache maintenance), R5
// contended single-address atomicAdd = +8us (serialized RMW tail).
// Main kernel streams 268.4MB at ~6 TB/s = ~9.8 B/cy/CU, at the per-CU
// streaming constant (m13: ~10 B/cy/CU). This is the roofline.

#define HDIM 4096
#define WDIM 4096
#define NBLOCKS 2048
#define NTHREADS 256
#define N4 ((2 * HDIM * WDIM) / 4)
#define STRIDE (NBLOCKS * NTHREADS)
#define ITERS (N4 / STRIDE)   // = 16
#define BATCH 4

__global__ __launch_bounds__(NTHREADS) void smooth_partial_kernel(
    const float4* __restrict__ x4,
    const float4* __restrict__ w4,
    double* __restrict__ partial)
{
    int tid = blockIdx.x * blockDim.x + threadIdx.x;

    double acc0 = 0.0, acc1 = 0.0, acc2 = 0.0, acc3 = 0.0;

    #pragma unroll
    for (int b = 0; b < ITERS; b += BATCH) {
        float4 xv[BATCH], wv[BATCH];
        #pragma unroll
        for (int k = 0; k < BATCH; ++k) {
            int i = tid + (b + k) * STRIDE;
            xv[k] = x4[i];
            wv[k] = w4[i];
        }
        #pragma unroll
        for (int k = 0; k < BATCH; ++k) {
            int i  = tid + (b + k) * STRIDE;
            int e  = i << 2;                 // flat element index of .x
            int ww = e & (WDIM - 1);         // column of .x
            int h  = (e >> 12) & (HDIM - 1); // row

            float nh  = 3.0f - (h == 0) - (h == HDIM - 1);
            float nw0 = (ww == 0)        ? 2.0f : 3.0f;
            float nw3 = (ww == WDIM - 4) ? 2.0f : 3.0f;
            float m1  = nh * 3.0f - 1.0f;

            acc0 += (double)(xv[k].x * (1.0f - (nh * nw0 - 1.0f) * wv[k].x));
            acc1 += (double)(xv[k].y * (1.0f - m1 * wv[k].y));
            acc2 += (double)(xv[k].z * (1.0f - m1 * wv[k].z));
            acc3 += (double)(xv[k].w * (1.0f - (nh * nw3 - 1.0f) * wv[k].w));
        }
    }

    double acc = (acc0 + acc1) + (acc2 + acc3);

    // wave(64) reduce
    for (int off = 32; off > 0; off >>= 1)
        acc += __shfl_down(acc, off, 64);

    __shared__ double lds[NTHREADS / 64];
    int lane = threadIdx.x & 63;
    int wid  = threadIdx.x >> 6;
    if (lane == 0) lds[wid] = acc;
    __syncthreads();

    if (threadIdx.x == 0) {
        double s = (lds[0] + lds[1]) + (lds[2] + lds[3]);
        partial[blockIdx.x] = s;
    }
}

__global__ __launch_bounds__(NTHREADS) void smooth_final_kernel(
    const double* __restrict__ partial,
    float* __restrict__ out)
{
    double acc = 0.0;
    #pragma unroll
    for (int j = 0; j < NBLOCKS / NTHREADS; ++j)   // 8 per thread
        acc += partial[threadIdx.x + j * NTHREADS];

    for (int off = 32; off > 0; off >>= 1)
        acc += __shfl_down(acc, off, 64);

    __shared__ double lds[NTHREADS / 64];
    int lane = threadIdx.x & 63;
    int wid  = threadIdx.x >> 6;
    if (lane == 0) lds[wid] = acc;
    __syncthreads();

    if (threadIdx.x == 0) {
        double s = (lds[0] + lds[1]) + (lds[2] + lds[3]);
        out[0] = (float)(s / ((double)HDIM * (double)WDIM));
    }
}

extern "C" void kernel_launch(void* const* d_in, const int* in_sizes, int n_in,
                              void* d_out, int out_size, void* d_ws, size_t ws_size,
                              hipStream_t stream) {
    const float4* x4 = (const float4*)d_in[0];
    const float4* w4 = (const float4*)d_in[1];
    float* out = (float*)d_out;
    double* partial = (double*)d_ws;   // NBLOCKS doubles = 16 KB

    (void)in_sizes; (void)n_in; (void)out_size; (void)ws_size;

    smooth_partial_kernel<<<NBLOCKS, NTHREADS, 0, stream>>>(x4, w4, partial);
    smooth_final_kernel<<<1, NTHREADS, 0, stream>>>(partial, out);
}